// Round 5
// baseline (2612.610 us; speedup 1.0000x reference)
//
#include <hip/hip_runtime.h>

// Encoder on 2048 identical disjoint K21 blocks.
// Key identity: Tk(A)(x) @ Wk == Tk(A) · (x @ Wk)
// => each ChebConv = ONE dense GEMM  Y = X @ [W_0|...|W_4]  (bf16 hi/lo split, 3-MFMA)
//    + tiny fused epilogue  out_b = sum_k Tk(21x21) @ Y_k,b  (+bias, relu) in f32.

typedef float f32x4 __attribute__((ext_vector_type(4)));
typedef short s16x8 __attribute__((ext_vector_type(8)));
typedef short s16x4 __attribute__((ext_vector_type(4)));

#define C21   21
#define EPER  420
#define HID   105
#define NBLK  2048
#define NNODE (NBLK*C21)   // 43008
#define FIN   1024
#define FMID  256
#define FOUT  64

// ws float offsets
#define TK_OFF  512
#define W1H_OFF 4096
#define W1L_OFF (W1H_OFF + 655360)
#define W2H_OFF (W1L_OFF + 655360)
#define W2L_OFF (W2H_OFF + 40960)
#define H_OFF   (W2L_OFF + 40960)

__device__ inline void split2(float f, short& h, short& l) {
  union { float f; unsigned u; } a; a.f = f;
  unsigned hb = (a.u + 0x7fffu + ((a.u >> 16) & 1u)) >> 16;   // RNE f32->bf16
  union { unsigned u; float f; } b; b.u = hb << 16;
  float r = f - b.f;
  union { float f; unsigned u; } c; c.f = r;
  unsigned lb = (c.u + 0x7fffu + ((c.u >> 16) & 1u)) >> 16;
  h = (short)hb; l = (short)lb;
}

// ---------------- edge-MLP + Tk(A) matrices ----------------
__global__ __launch_bounds__(256) void k_adj(
    const float* __restrict__ ew, const float* __restrict__ Wfc1,
    const float* __restrict__ Wfc2, float* __restrict__ ws,
    float* __restrict__ out_ew)
{
  __shared__ float ews[EPER];
  __shared__ float h1[HID];
  __shared__ float h2[EPER];
  __shared__ float dis[C21];
  __shared__ float Als[441], Ta[441], Tb[441], Tc[441];
  const int tid = threadIdx.x;
  for (int i = tid; i < EPER; i += 256) ews[i] = ew[i];
  __syncthreads();
  for (int m = tid; m < HID; m += 256) {
    float s = 0.f;
    for (int e = 0; e < EPER; ++e) s = fmaf(ews[e], Wfc1[e*HID + m], s);
    h1[m] = s > 0.f ? s : (expf(s) - 1.f);
  }
  __syncthreads();
  for (int j = tid; j < EPER; j += 256) {
    float s = 0.f;
    for (int m = 0; m < HID; ++m) s = fmaf(h1[m], Wfc2[m*EPER + j], s);
    float v = tanhf(s);
    v = v > 0.f ? v : 0.f;
    h2[j] = v; ws[j] = v; out_ew[j] = v;
  }
  __syncthreads();
  if (tid < C21) {
    float d = 0.f;
    for (int j = 0; j < C21; ++j) {
      if (j == tid) continue;
      d += h2[tid*20 + (j < tid ? j : j - 1)];
    }
    dis[tid] = d > 0.f ? 1.f / sqrtf(d) : 0.f;
  }
  __syncthreads();
  for (int idx = tid; idx < 441; idx += 256) {
    const int jd = idx / C21, is = idx % C21;           // row=dst, col=src
    float a = 0.f;
    if (is != jd)
      a = -(dis[is] * h2[is*20 + (jd < is ? jd : jd - 1)] * dis[jd]);
    Als[idx] = a;
  }
  __syncthreads();
  for (int idx = tid; idx < 441; idx += 256) {
    const int i = idx / C21, l = idx % C21;
    float t0 = (i == l) ? 1.f : 0.f;
    Ta[idx] = t0; Tb[idx] = Als[idx];
    ws[TK_OFF + idx] = t0;
    ws[TK_OFF + 441 + idx] = Als[idx];
  }
  __syncthreads();
  float* P = Ta; float* Q = Tb; float* R = Tc;
  for (int k = 2; k < 5; ++k) {
    for (int idx = tid; idx < 441; idx += 256) {
      const int i = idx / C21, l = idx % C21;
      float s = 0.f;
      for (int m = 0; m < C21; ++m) s = fmaf(Als[i*C21 + m], Q[m*C21 + l], s);
      float v = 2.f*s - P[idx];
      R[idx] = v;
      ws[TK_OFF + k*441 + idx] = v;
    }
    __syncthreads();
    float* t = P; P = Q; Q = R; R = t;
  }
}

// ---------------- tile ew -> train_ew ----------------
__global__ __launch_bounds__(256) void k_tile(
    const float* __restrict__ ws, float* __restrict__ out_tew)
{
  const int idx = blockIdx.x * 256 + threadIdx.x;
  if (idx < NBLK*EPER) out_tew[idx] = ws[idx % EPER];
}

// ---------------- W -> bf16 hi/lo MFMA-fragment prep ----------------
__global__ __launch_bounds__(256) void k_wprep(
    const float* __restrict__ W, short* __restrict__ wh, short* __restrict__ wl,
    int njt, int kscnt, int wcols, int kdim)
{
  const int gw = (blockIdx.x*256 + threadIdx.x) >> 6;
  const int lane = threadIdx.x & 63;
  const int nt = gw / kscnt, ks = gw % kscnt;
  const int kslice = nt / njt, jt = nt % njt;
  const int j = jt*16 + (lane & 15);
  const int f0 = ks*32 + ((lane >> 4) << 3);
  const float* src = W + (size_t)kslice*kdim*wcols + (size_t)f0*wcols + j;
  s16x8 hv, lv;
#pragma unroll
  for (int e = 0; e < 8; ++e) {
    short h, l;
    split2(src[(size_t)e*wcols], h, l);
    hv[e] = h; lv[e] = l;
  }
  const size_t off = ((size_t)gw*64 + lane)*8;
  *(s16x8*)(wh + off) = hv;
  *(s16x8*)(wl + off) = lv;
}

// ---------------- fused GEMM (bf16 split MFMA) + Tk-combine epilogue ----------------
// M-tile 192 (168 real rows = 8 graph blocks), 8 waves (2M x 4N).
// 1-D grid; XCD-chunked swizzle, y (column group) fastest => the NY column
// groups of one X panel run temporally adjacent on the same XCD L2.
template<int KDIM, int OUTW, bool RELU, int NY>
__global__ __launch_bounds__(512, 4) void k_cheb(
    const float* __restrict__ in, const short* __restrict__ wh,
    const short* __restrict__ wl, const float* __restrict__ bias,
    const float* __restrict__ tkg, float* __restrict__ outp)
{
  constexpr int NJT = OUTW / 16;
  constexpr int KS  = KDIM / 32;
  const int tid  = threadIdx.x;
  const int lane = tid & 63, wave = tid >> 6;
  const int wm = wave >> 2, wn = wave & 3;

  const int b = blockIdx.x, total = gridDim.x;
  const int L = (b & 7) * (total >> 3) + (b >> 3);     // XCD-chunked (total%8==0)
  const int bx = L / NY, by = L % NY;
  const int rowBase = bx * 168;
  const int jbase = by * 64;
  const int jt = by*4 + wn;

  __shared__ short s_a[2*192*72];            // Ah | Al (bf16); reused as swizzled f32 Y
  short* sAh = s_a;
  short* sAl = s_a + 192*72;

  f32x4 acc[6][5];
#pragma unroll
  for (int mi = 0; mi < 6; ++mi)
#pragma unroll
    for (int cs = 0; cs < 5; ++cs) acc[mi][cs] = (f32x4){0.f,0.f,0.f,0.f};

  const int r0 = tid >> 4, cq = (tid & 15) * 4;
  f32x4 xreg[6];
  auto loadX = [&](int kc) {
#pragma unroll
    for (int ii = 0; ii < 6; ++ii) {
      const int r = r0 + 32*ii;
      if (r < 168)
        xreg[ii] = *(const f32x4*)(in + (size_t)(rowBase + r)*KDIM + kc*64 + cq);
      else
        xreg[ii] = (f32x4){0.f,0.f,0.f,0.f};
    }
  };

  const short* whp = wh + (size_t)jt*KS*512 + (size_t)lane*8;
  const short* wlp = wl + (size_t)jt*KS*512 + (size_t)lane*8;

  loadX(0);
  for (int kc = 0; kc < KDIM/64; ++kc) {
    __syncthreads();
    // stage regs -> LDS as bf16 hi/lo, row stride 72 shorts (144B: conflict-free)
#pragma unroll
    for (int ii = 0; ii < 6; ++ii) {
      const int r = r0 + 32*ii;
      s16x4 hv, lv;
#pragma unroll
      for (int c = 0; c < 4; ++c) {
        short h, l;
        split2(xreg[ii][c], h, l);
        hv[c] = h; lv[c] = l;
      }
      *(s16x4*)&sAh[r*72 + cq] = hv;
      *(s16x4*)&sAl[r*72 + cq] = lv;
    }
    __syncthreads();
    if (kc + 1 < KDIM/64) loadX(kc + 1);      // T14: issue next chunk under MFMA

#pragma unroll
    for (int kstep = 0; kstep < 2; ++kstep) {
      const int ksg = kc*2 + kstep;
      s16x8 bh[5], bl[5];
#pragma unroll
      for (int cs = 0; cs < 5; ++cs) {
        const size_t o = (size_t)cs*NJT*KS*512 + (size_t)ksg*512;
        bh[cs] = *(const s16x8*)(whp + o);
        bl[cs] = *(const s16x8*)(wlp + o);
      }
      const int kcol = kstep*32 + (lane >> 4)*8;
#pragma unroll
      for (int mi = 0; mi < 6; ++mi) {
        const int row = wm*96 + mi*16 + (lane & 15);
        const s16x8 ah = *(const s16x8*)&sAh[row*72 + kcol];
        const s16x8 al = *(const s16x8*)&sAl[row*72 + kcol];
#pragma unroll
        for (int cs = 0; cs < 5; ++cs) {
          acc[mi][cs] = __builtin_amdgcn_mfma_f32_16x16x32_bf16(al, bh[cs], acc[mi][cs], 0, 0, 0);
          acc[mi][cs] = __builtin_amdgcn_mfma_f32_16x16x32_bf16(ah, bl[cs], acc[mi][cs], 0, 0, 0);
          acc[mi][cs] = __builtin_amdgcn_mfma_f32_16x16x32_bf16(ah, bh[cs], acc[mi][cs], 0, 0, 0);
        }
      }
    }
  }

  // epilogue: out_b = sum_k Tk @ Y_k,b  (+bias, relu). wave == graph block g.
  // Y stored swizzled: idx(row,col) = row*64 + ((col + 4*row) & 63)  -> 2-way max
  float* Y = (float*)s_a;
  float oacc[C21];
  const float bv = bias[jbase + lane];
#pragma unroll
  for (int i = 0; i < C21; ++i) oacc[i] = bv;

  for (int k = 0; k < 5; ++k) {
    __syncthreads();
#pragma unroll
    for (int mi = 0; mi < 6; ++mi) {
      const int rr = wm*96 + mi*16 + (lane >> 4)*4;
      const int cc = wn*16 + (lane & 15);
#pragma unroll
      for (int r = 0; r < 4; ++r) {
        const int row = rr + r;
        Y[row*64 + ((cc + 4*row) & 63)] = acc[mi][k][r];
      }
    }
    __syncthreads();
    const float* tk = tkg + k*441;            // wave-uniform -> s_load
    float yl[C21];
#pragma unroll
    for (int l = 0; l < C21; ++l) {
      const int row = wave*C21 + l;
      yl[l] = Y[row*64 + ((lane + 4*row) & 63)];
    }
#pragma unroll
    for (int i = 0; i < C21; ++i) {
      float s = oacc[i];
#pragma unroll
      for (int l = 0; l < C21; ++l) s = fmaf(tk[i*C21 + l], yl[l], s);
      oacc[i] = s;
    }
  }

#pragma unroll
  for (int i = 0; i < C21; ++i) {
    float v = oacc[i];
    if (RELU) v = fmaxf(v, 0.f);
    outp[(size_t)(rowBase + wave*C21 + i)*OUTW + jbase + lane] = v;
  }
}

extern "C" void kernel_launch(void* const* d_in, const int* in_sizes, int n_in,
                              void* d_out, int out_size, void* d_ws, size_t ws_size,
                              hipStream_t stream) {
  const float* x    = (const float*)d_in[0];
  const float* ew   = (const float*)d_in[2];
  const float* Wfc1 = (const float*)d_in[3];
  const float* Wfc2 = (const float*)d_in[4];
  const float* W1   = (const float*)d_in[5];
  const float* b1   = (const float*)d_in[6];
  const float* W2   = (const float*)d_in[7];
  const float* b2   = (const float*)d_in[8];

  float* out     = (float*)d_out;
  float* out_ew  = out + (size_t)NNODE * FOUT;
  float* out_tew = out_ew + EPER;
  float* wsf     = (float*)d_ws;
  short* w1h = (short*)(wsf + W1H_OFF);
  short* w1l = (short*)(wsf + W1L_OFF);
  short* w2h = (short*)(wsf + W2H_OFF);
  short* w2l = (short*)(wsf + W2L_OFF);
  float* hbuf = wsf + H_OFF;

  k_adj <<<1, 256, 0, stream>>>(ew, Wfc1, Wfc2, wsf, out_ew);
  k_tile<<<(NBLK*EPER + 255)/256, 256, 0, stream>>>(wsf, out_tew);
  k_wprep<<<640, 256, 0, stream>>>(W1, w1h, w1l, 16, 32, FMID, FIN);
  k_wprep<<<40,  256, 0, stream>>>(W2, w2h, w2l, 4,  8,  FOUT, FMID);
  k_cheb<FIN,  FMID, true,  4><<<1024, 512, 0, stream>>>(x,    w1h, w1l, b1, wsf + TK_OFF, hbuf);
  k_cheb<FMID, FOUT, false, 1><<<256,  512, 0, stream>>>(hbuf, w2h, w2l, b2, wsf + TK_OFF, out);
}

// Round 6
// 697.633 us; speedup vs baseline: 3.7450x; 3.7450x over previous
//
#include <hip/hip_runtime.h>

// Encoder on 2048 identical disjoint K21 blocks.
// ChebConv = ONE dense GEMM Y = X @ [W0|..|W4] (bf16 hi/lo split, 3-MFMA)
//  + fused epilogue out_b = sum_k Tk(21x21) @ Y_k,b (+bias, relu).
// A-path: f32 DMA (global_load_lds, dbuf, XOR-swizzled) + in-register trunc split.

typedef float f32x4 __attribute__((ext_vector_type(4)));
typedef short s16x8 __attribute__((ext_vector_type(8)));

#define C21   21
#define EPER  420
#define HID   105
#define NBLK  2048
#define NNODE (NBLK*C21)   // 43008
#define FIN   1024
#define FMID  256
#define FOUT  64

#define TK_OFF  512
#define W1H_OFF 4096
#define W1L_OFF (W1H_OFF + 655360)
#define W2H_OFF (W1L_OFF + 655360)
#define W2L_OFF (W2H_OFF + 40960)
#define H_OFF   (W2L_OFF + 40960)        // h: 43008x256 f32  (total ~50 MB, proven)

__device__ inline void split2(float f, short& h, short& l) {
  union { float f; unsigned u; } a; a.f = f;
  unsigned hb = (a.u + 0x7fffu + ((a.u >> 16) & 1u)) >> 16;   // RNE f32->bf16
  union { unsigned u; float f; } b; b.u = hb << 16;
  float r = f - b.f;
  union { float f; unsigned u; } c; c.f = r;
  unsigned lb = (c.u + 0x7fffu + ((c.u >> 16) & 1u)) >> 16;
  h = (short)hb; l = (short)lb;
}

// ---------------- edge-MLP + Tk(A) matrices ----------------
__global__ __launch_bounds__(256) void k_adj(
    const float* __restrict__ ew, const float* __restrict__ Wfc1,
    const float* __restrict__ Wfc2, float* __restrict__ ws,
    float* __restrict__ out_ew)
{
  __shared__ float ews[EPER];
  __shared__ float h1[HID];
  __shared__ float h2[EPER];
  __shared__ float dis[C21];
  __shared__ float Als[441], Ta[441], Tb[441], Tc[441];
  const int tid = threadIdx.x;
  for (int i = tid; i < EPER; i += 256) ews[i] = ew[i];
  __syncthreads();
  for (int m = tid; m < HID; m += 256) {
    float s = 0.f;
    for (int e = 0; e < EPER; ++e) s = fmaf(ews[e], Wfc1[e*HID + m], s);
    h1[m] = s > 0.f ? s : (expf(s) - 1.f);
  }
  __syncthreads();
  for (int j = tid; j < EPER; j += 256) {
    float s = 0.f;
    for (int m = 0; m < HID; ++m) s = fmaf(h1[m], Wfc2[m*EPER + j], s);
    float v = tanhf(s);
    v = v > 0.f ? v : 0.f;
    h2[j] = v; ws[j] = v; out_ew[j] = v;
  }
  __syncthreads();
  if (tid < C21) {
    float d = 0.f;
    for (int j = 0; j < C21; ++j) {
      if (j == tid) continue;
      d += h2[tid*20 + (j < tid ? j : j - 1)];
    }
    dis[tid] = d > 0.f ? 1.f / sqrtf(d) : 0.f;
  }
  __syncthreads();
  for (int idx = tid; idx < 441; idx += 256) {
    const int jd = idx / C21, is = idx % C21;           // row=dst, col=src
    float a = 0.f;
    if (is != jd)
      a = -(dis[is] * h2[is*20 + (jd < is ? jd : jd - 1)] * dis[jd]);
    Als[idx] = a;
  }
  __syncthreads();
  for (int idx = tid; idx < 441; idx += 256) {
    const int i = idx / C21, l = idx % C21;
    float t0 = (i == l) ? 1.f : 0.f;
    Ta[idx] = t0; Tb[idx] = Als[idx];
    ws[TK_OFF + idx] = t0;
    ws[TK_OFF + 441 + idx] = Als[idx];
  }
  __syncthreads();
  float* P = Ta; float* Q = Tb; float* R = Tc;
  for (int k = 2; k < 5; ++k) {
    for (int idx = tid; idx < 441; idx += 256) {
      const int i = idx / C21, l = idx % C21;
      float s = 0.f;
      for (int m = 0; m < C21; ++m) s = fmaf(Als[i*C21 + m], Q[m*C21 + l], s);
      float v = 2.f*s - P[idx];
      R[idx] = v;
      ws[TK_OFF + k*441 + idx] = v;
    }
    __syncthreads();
    float* t = P; P = Q; Q = R; R = t;
  }
}

// ---------------- tile ew -> train_ew ----------------
__global__ __launch_bounds__(256) void k_tile(
    const float* __restrict__ ws, float* __restrict__ out_tew)
{
  const int idx = blockIdx.x * 256 + threadIdx.x;
  if (idx < NBLK*EPER) out_tew[idx] = ws[idx % EPER];
}

// ---------------- W -> bf16 hi/lo MFMA-fragment prep ----------------
// frag (nt, ks, lane, e) = W[kslice][f = ks*32+(lane>>4)*8+e][j = (nt%njt)*16+(lane&15)]
__global__ __launch_bounds__(256) void k_wprep(
    const float* __restrict__ W, short* __restrict__ wh, short* __restrict__ wl,
    int njt, int kscnt, int wcols, int kdim)
{
  const int gw = (blockIdx.x*256 + threadIdx.x) >> 6;
  const int lane = threadIdx.x & 63;
  const int nt = gw / kscnt, ks = gw % kscnt;
  const int kslice = nt / njt, jt = nt % njt;
  const int j = jt*16 + (lane & 15);
  const int f0 = ks*32 + ((lane >> 4) << 3);
  const float* src = W + (size_t)kslice*kdim*wcols + (size_t)f0*wcols + j;
  s16x8 hv, lv;
#pragma unroll
  for (int e = 0; e < 8; ++e) {
    short h, l;
    split2(src[(size_t)e*wcols], h, l);
    hv[e] = h; lv[e] = l;
  }
  const size_t off = ((size_t)gw*64 + lane)*8;
  *(s16x8*)(wh + off) = hv;
  *(s16x8*)(wl + off) = lv;
}

// ---------------- fused GEMM + Tk-combine epilogue ----------------
// M-tile 192 (168 real rows = 8 gblocks), 8 waves (2M x 4N), no VGPR cap.
template<int KDIM, int OUTW, bool RELU, int NY>
__global__ __launch_bounds__(512) void k_cheb(
    const float* __restrict__ in, const short* __restrict__ wh,
    const short* __restrict__ wl, const float* __restrict__ bias,
    const float* __restrict__ tkg, float* __restrict__ outp)
{
  constexpr int NJT = OUTW / 16;
  constexpr int KS  = KDIM / 32;
  constexpr int KC  = KDIM / 64;
  const int tid  = threadIdx.x;
  const int lane = tid & 63, wave = tid >> 6;
  const int wm = wave >> 2, wn = wave & 3;

  const int b = blockIdx.x, total = gridDim.x;
  const int L = (b & 7) * (total >> 3) + (b >> 3);     // XCD-chunked (total%8==0)
  const int bx = L / NY, by = L % NY;
  const int rowBase = bx * 168;
  const int jbase = by * 64;
  const int jt = by*4 + wn;

  __shared__ float lbuf[2][192*64];          // 2 x 48 KB dbuf; lbuf[0] reused as Y

  f32x4 acc[6][5];
#pragma unroll
  for (int mi = 0; mi < 6; ++mi)
#pragma unroll
    for (int cs = 0; cs < 5; ++cs) acc[mi][cs] = (f32x4){0.f,0.f,0.f,0.f};

  // DMA stage k-chunk kc into lbuf[d]: 192 rows x 16 chunks(16B), source XOR-swz.
  // LDS slot (row,c) holds global chunk (c ^ (row&15)); reads undo the XOR.
  auto stage = [&](int kc, int d) {
    float* base = &lbuf[d][0];
#pragma unroll
    for (int j = 0; j < 6; ++j) {
      const int slot = j*512 + tid;
      const int row = slot >> 4, c = slot & 15;
      int grow = rowBase + row; grow = grow < NNODE ? grow : NNODE - 1;  // clamp OOB
      const float* g = in + (size_t)grow*KDIM + kc*64 + ((c ^ (row & 15)) << 2);
      __builtin_amdgcn_global_load_lds(
          (const __attribute__((address_space(1))) void*)g,
          (__attribute__((address_space(3))) void*)(base + (size_t)(j*512 + (wave << 6))*4),
          16, 0, 0);
    }
  };

  // trunc hi/lo pack: 2 f32 -> 1 dword of hi-bf16s + 1 dword of lo-bf16s
  auto pk = [&](float x0, float x1, unsigned& H, unsigned& Lo) {
    unsigned u0 = __float_as_uint(x0), u1 = __float_as_uint(x1);
    H = __builtin_amdgcn_perm(u1, u0, 0x07060302u);
    float r0 = x0 - __uint_as_float(u0 & 0xffff0000u);
    float r1 = x1 - __uint_as_float(u1 & 0xffff0000u);
    Lo = __builtin_amdgcn_perm(__float_as_uint(r1), __float_as_uint(r0), 0x07060302u);
  };

  const short* whp = wh + (size_t)jt*KS*512 + (size_t)lane*8;
  const short* wlp = wl + (size_t)jt*KS*512 + (size_t)lane*8;

  stage(0, 0);
  for (int kc = 0; kc < KC; ++kc) {
    const int cur = kc & 1;
    __syncthreads();                         // compiler drains vmcnt -> DMA landed
    if (kc + 1 < KC) stage(kc + 1, cur ^ 1); // prefetch under this kc's MFMAs

#pragma unroll
    for (int ks = 0; ks < 2; ++ks) {
      const int ksg = kc*2 + ks;
      s16x8 bh[5], bl[5];
#pragma unroll
      for (int cs = 0; cs < 5; ++cs) {
        const size_t o = ((size_t)cs*NJT*KS + ksg)*512;
        bh[cs] = *(const s16x8*)(whp + o);
        bl[cs] = *(const s16x8*)(wlp + o);
      }
      const int cpre = ks*8 + (lane >> 4)*2;
#pragma unroll
      for (int mi = 0; mi < 6; ++mi) {
        const int row = wm*96 + mi*16 + (lane & 15);
        const int sw = row & 15;
        const f32x4 fa = *(const f32x4*)&lbuf[cur][(size_t)row*64 + ((cpre ^ sw) << 2)];
        const f32x4 fb = *(const f32x4*)&lbuf[cur][(size_t)row*64 + ((((cpre + 1)) ^ sw) << 2)];
        unsigned h0,h1,h2,h3,l0,l1,l2,l3;
        pk(fa[0], fa[1], h0, l0);
        pk(fa[2], fa[3], h1, l1);
        pk(fb[0], fb[1], h2, l2);
        pk(fb[2], fb[3], h3, l3);
        union { unsigned u[4]; s16x8 v; } AH = {{h0,h1,h2,h3}}, AL = {{l0,l1,l2,l3}};
        const s16x8 ah = AH.v, al = AL.v;
#pragma unroll
        for (int cs = 0; cs < 5; ++cs) {
          acc[mi][cs] = __builtin_amdgcn_mfma_f32_16x16x32_bf16(al, bh[cs], acc[mi][cs], 0, 0, 0);
          acc[mi][cs] = __builtin_amdgcn_mfma_f32_16x16x32_bf16(ah, bl[cs], acc[mi][cs], 0, 0, 0);
          acc[mi][cs] = __builtin_amdgcn_mfma_f32_16x16x32_bf16(ah, bh[cs], acc[mi][cs], 0, 0, 0);
        }
      }
    }
  }

  // epilogue: out_b = sum_k Tk @ Y_k,b (+bias, relu). wave == graph block.
  // Y swizzled on 16B chunks: idx = row*64 + (((c>>?)^(row&15))<<2 | ...)
  float* Y = &lbuf[0][0];
  float oacc[C21];
  const float bv = bias[jbase + lane];
#pragma unroll
  for (int i = 0; i < C21; ++i) oacc[i] = bv;

  for (int k = 0; k < 5; ++k) {
    __syncthreads();
#pragma unroll
    for (int mi = 0; mi < 6; ++mi) {
      const int rr = wm*96 + mi*16 + (lane >> 4)*4;
      const int cc = wn*16 + (lane & 15);
#pragma unroll
      for (int r = 0; r < 4; ++r) {
        const int row = rr + r;
        Y[row*64 + ((((cc >> 2) ^ (row & 15)) << 2) | (cc & 3))] = acc[mi][k][r];
      }
    }
    __syncthreads();
    const float* tk = tkg + k*441;            // wave-uniform -> s_load
    float yl[C21];
#pragma unroll
    for (int l = 0; l < C21; ++l) {
      const int row = wave*C21 + l;
      yl[l] = Y[row*64 + ((((lane >> 2) ^ (row & 15)) << 2) | (lane & 3))];
    }
#pragma unroll
    for (int i = 0; i < C21; ++i) {
      float s = oacc[i];
#pragma unroll
      for (int l = 0; l < C21; ++l) s = fmaf(tk[i*C21 + l], yl[l], s);
      oacc[i] = s;
    }
  }

#pragma unroll
  for (int i = 0; i < C21; ++i) {
    float v = oacc[i];
    if (RELU) v = fmaxf(v, 0.f);
    outp[(size_t)(rowBase + wave*C21 + i)*OUTW + jbase + lane] = v;
  }
}

extern "C" void kernel_launch(void* const* d_in, const int* in_sizes, int n_in,
                              void* d_out, int out_size, void* d_ws, size_t ws_size,
                              hipStream_t stream) {
  const float* x    = (const float*)d_in[0];
  const float* ew   = (const float*)d_in[2];
  const float* Wfc1 = (const float*)d_in[3];
  const float* Wfc2 = (const float*)d_in[4];
  const float* W1   = (const float*)d_in[5];
  const float* b1   = (const float*)d_in[6];
  const float* W2   = (const float*)d_in[7];
  const float* b2   = (const float*)d_in[8];

  float* out     = (float*)d_out;
  float* out_ew  = out + (size_t)NNODE * FOUT;
  float* out_tew = out_ew + EPER;
  float* wsf     = (float*)d_ws;
  short* w1h = (short*)(wsf + W1H_OFF);
  short* w1l = (short*)(wsf + W1L_OFF);
  short* w2h = (short*)(wsf + W2H_OFF);
  short* w2l = (short*)(wsf + W2L_OFF);
  float* hbuf = wsf + H_OFF;

  k_adj <<<1, 256, 0, stream>>>(ew, Wfc1, Wfc2, wsf, out_ew);
  k_tile<<<(NBLK*EPER + 255)/256, 256, 0, stream>>>(wsf, out_tew);
  k_wprep<<<640, 256, 0, stream>>>(W1, w1h, w1l, 16, 32, FMID, FIN);
  k_wprep<<<40,  256, 0, stream>>>(W2, w2h, w2l, 4,  8,  FOUT, FMID);
  k_cheb<FIN,  FMID, true,  4><<<1024, 512, 0, stream>>>(x,    w1h, w1l, b1, wsf + TK_OFF, hbuf);
  k_cheb<FMID, FOUT, false, 1><<<256,  512, 0, stream>>>(hbuf, w2h, w2l, b2, wsf + TK_OFF, out);
}